// Round 3
// baseline (1038.949 us; speedup 1.0000x reference)
//
#include <hip/hip_runtime.h>

#define B_    1024
#define S_    50
#define L_    20
#define NOUT  100001

typedef __attribute__((ext_vector_type(8))) short bh8;   // 8 bf16 (4 VGPRs)
typedef __attribute__((ext_vector_type(4))) float fx4;   // MFMA C/D

__device__ __forceinline__ unsigned short f2bf(float x){
  unsigned u = __float_as_uint(x);
  unsigned r = (u + 0x7FFFu + ((u >> 16) & 1u)) >> 16;   // RNE
  return (unsigned short)r;
}
__device__ __forceinline__ float bf2f(unsigned short h){
  return __uint_as_float(((unsigned)h) << 16);
}
__device__ __forceinline__ float sigm(float x){
  return __builtin_amdgcn_rcpf(1.f + __expf(-x));
}
__device__ __forceinline__ float tanh_(float x){
  return 1.f - 2.f*__builtin_amdgcn_rcpf(__expf(2.f*x) + 1.f);
}

// split x into bf16 hi + bf16 lo (hi+lo == x to ~2^-17 rel)
__device__ __forceinline__ void frag_convert_row(const float* src, bh8& hv, bh8& lv){
  #pragma unroll
  for (int j = 0; j < 8; j++){
    float x = src[j];
    unsigned short hb = f2bf(x);
    hv[j] = (short)hb;
    lv[j] = (short)f2bf(x - bf2f(hb));
  }
}

// ---------------------------------------------------------------------------
// LSTM weight prep: single bf16 plane in per-lane B-fragment order.
// Layout: [layer(2)][nt(32)][kt(8)][lane(64)][8 bf16]
// B-frag (16x16x32): n = nt*16 + (lane&15), k = kt*32 + (lane>>4)*8 + j.
// K=256 = [x(128) | h(128)] -> W_ih cols then W_hh cols. bias = b_ih + b_hh.
__global__ __launch_bounds__(256) void prep_lstm_w(
    const float* __restrict__ Wih0, const float* __restrict__ Whh0,
    const float* __restrict__ bih0, const float* __restrict__ bhh0,
    const float* __restrict__ Wih1, const float* __restrict__ Whh1,
    const float* __restrict__ bih1, const float* __restrict__ bhh1,
    short* __restrict__ wsw, float* __restrict__ wsbias){
  int tid = blockIdx.x*256 + threadIdx.x;       // 32768 total
  if (tid < 1024){
    int l = tid >> 9, n = tid & 511;
    wsbias[l*512 + n] = l ? (bih1[n] + bhh1[n]) : (bih0[n] + bhh0[n]);
  }
  if (tid >= 32768) return;
  int lane = tid & 63;
  int kt   = (tid >> 6) & 7;
  int nt   = (tid >> 9) & 31;
  int l    = tid >> 14;
  const float* Wih = l ? Wih1 : Wih0;
  const float* Whh = l ? Whh1 : Whh0;
  int n = nt*16 + (lane & 15);
  int kbase = kt*32 + (lane >> 4)*8;
  size_t base = ((((size_t)l*32 + nt)*8 + kt)*64 + lane)*8;
  for (int j = 0; j < 8; j++){
    int k = kbase + j;
    float w = (k < 128) ? Wih[n*128 + k] : Whh[n*128 + (k - 128)];
    wsw[base + j] = (short)f2bf(w);
  }
}

// W2 -> bf16, padded to 100016 rows (zeros).
__global__ __launch_bounds__(256) void prep_w2(const float* __restrict__ W2,
                                               short* __restrict__ out){
  long i = (long)blockIdx.x*256 + threadIdx.x;  // 100016*64 = 6,401,024
  if (i >= 100016L*64) return;
  long row = i >> 6;
  float v = (row < NOUT) ? W2[i] : 0.f;
  out[i] = (short)f2bf(v);
}

// ---------------------------------------------------------------------------
// Features -> x in A-fragment order, bf16 hi/lo planes.
// xfrag layout: [s(50)][bt(64)][plane(2)][kt(4)][lane(64)][8 bf16]
// Block = (bt, s): 16 batch rows x 128 features.
__global__ __launch_bounds__(256) void features(
    const int* __restrict__ pidx, const int* __restrict__ cidx,
    const float* __restrict__ age, const float* __restrict__ ts,
    const float* __restrict__ gender,
    const float* __restrict__ embp, const float* __restrict__ embc,
    const float* __restrict__ Wts, const float* __restrict__ bts,
    const float* __restrict__ Wuf, const float* __restrict__ bufv,
    short* __restrict__ xfrag){
  const int bx = blockIdx.x;
  const int bt = bx & 63, s = bx >> 6;
  const int b0 = bt*16;
  const int tid = threadIdx.x;
  __shared__ int pi[320], ci[320];
  __shared__ __align__(16) float XF[16][132];
  for (int i = tid; i < 640; i += 256){
    if (i < 320){
      int row = i/20, l = i - row*20;
      pi[i] = pidx[((size_t)(b0+row)*S_ + s)*L_ + l];
    } else {
      int j = i - 320;
      int row = j/20, l = j - row*20;
      ci[j] = cidx[((size_t)(b0+row)*S_ + s)*L_ + l];
    }
  }
  __syncthreads();
  const int m = tid >> 4, fg = tid & 15;
  float a[8];
  if (fg < 8){
    int f0 = fg*8;
    float4 s0 = {0,0,0,0}, s1 = {0,0,0,0};
    for (int l = 0; l < L_; l++){
      const float4* p = (const float4*)(embp + (size_t)pi[m*20+l]*64 + f0);
      float4 u = p[0], v = p[1];
      s0.x += u.x; s0.y += u.y; s0.z += u.z; s0.w += u.w;
      s1.x += v.x; s1.y += v.y; s1.z += v.z; s1.w += v.w;
    }
    a[0]=s0.x*0.05f; a[1]=s0.y*0.05f; a[2]=s0.z*0.05f; a[3]=s0.w*0.05f;
    a[4]=s1.x*0.05f; a[5]=s1.y*0.05f; a[6]=s1.z*0.05f; a[7]=s1.w*0.05f;
  } else if (fg < 12){
    int f0 = (fg-8)*8;
    float4 s0 = {0,0,0,0}, s1 = {0,0,0,0};
    for (int l = 0; l < L_; l++){
      const float4* p = (const float4*)(embc + (size_t)ci[m*20+l]*32 + f0);
      float4 u = p[0], v = p[1];
      s0.x += u.x; s0.y += u.y; s0.z += u.z; s0.w += u.w;
      s1.x += v.x; s1.y += v.y; s1.z += v.z; s1.w += v.w;
    }
    a[0]=s0.x*0.05f; a[1]=s0.y*0.05f; a[2]=s0.z*0.05f; a[3]=s0.w*0.05f;
    a[4]=s1.x*0.05f; a[5]=s1.y*0.05f; a[6]=s1.z*0.05f; a[7]=s1.w*0.05f;
  } else if (fg < 14){
    int j0 = (fg-12)*8;
    float tv = ts[(size_t)(b0+m)*S_ + s];
    #pragma unroll
    for (int e = 0; e < 8; e++) a[e] = tv*Wts[j0+e] + bts[j0+e];
  } else {
    int j0 = (fg-14)*8;
    float av = age[b0+m], gv = gender[b0+m];
    #pragma unroll
    for (int e = 0; e < 8; e++){
      int j = j0+e;
      a[e] = av*Wuf[2*j] + gv*Wuf[2*j+1] + bufv[j];
    }
  }
  {
    int f0 = fg*8;
    *(float4*)&XF[m][f0]   = (float4){a[0],a[1],a[2],a[3]};
    *(float4*)&XF[m][f0+4] = (float4){a[4],a[5],a[6],a[7]};
  }
  __syncthreads();
  // phase 2: emit fragment-order hi/lo planes
  const int kt = tid >> 6, ls = tid & 63;
  const int mm = ls & 15, a2 = ls >> 4;
  bh8 hv, lv;
  frag_convert_row(&XF[mm][kt*32 + a2*8], hv, lv);
  size_t ob = ((((size_t)s*64 + bt)*2 + 0)*4 + kt)*512 + (size_t)ls*8;
  *(bh8*)(xfrag + ob)        = hv;   // plane 0 (hi)
  *(bh8*)(xfrag + ob + 2048) = lv;   // plane 1 (lo)
}

// ---------------------------------------------------------------------------
// 2-layer LSTM, layer-pipelined wave teams, WEIGHT-STATIONARY.
// 64 blocks x 1024 thr (16 waves, 4/SIMD). Waves 0-7: layer0 step i; waves
// 8-15: layer1 step i-1. Wave u owns cols [u*16,u*16+16) (nt=g*8+u).
// Weight residency per wave (32 frags of 1KB):
//   - 14 in registers  (gates 0,1 kt0-6; 56 VGPR, loaded once)
//   - 5  in LDS pool   (gate 2 kt0-4; 16 waves x 5KB = 80KB, staged once,
//                       wave-local reads -> no barrier needed)
//   - 13 streamed from L2 per step, issue staged (<=6 in flight) to stay
//     under the 128-VGPR cap at 4 waves/SIMD.
// This cuts per-CU weight traffic 512KB -> 208KB per step (the round-2
// bottleneck: L1 can't hold 512KB so every step re-pulled it from L2).
// Accumulation order per gate is unchanged -> bitwise-identical results.
__global__ __launch_bounds__(1024, 4) void lstm_kernel(
    const short* __restrict__ xfrag, const short* __restrict__ wsw,
    const float* __restrict__ wsbias,
    const float* __restrict__ W1, const float* __restrict__ b1,
    short* __restrict__ hidden_bf){
  __shared__ __align__(16) short XAhi[2][2048], XAlo[2][2048]; // x(t) frags
  __shared__ __align__(16) short H0hi[2][2048], H0lo[2][2048]; // h0(t) frags
  __shared__ __align__(16) short H1hi[2][2048], H1lo[2][2048]; // h1(t) frags
  __shared__ __align__(16) float XH0f[16][132], XH1f[16][132]; // f32 C-tiles
  __shared__ __align__(16) short WPOOL[40960];                 // 80KB weight pool
  const int tid  = threadIdx.x;
  const int w    = tid >> 6, lane = tid & 63;
  const int col  = lane & 15, quad = lane >> 4;
  const int bt   = blockIdx.x;
  const int u    = w & 7;                 // team-wave index (0..7)
  const bool t1  = (w >= 8);              // team1 = layer 1
  const int lsel = t1 ? 1 : 0;
  const int pl2  = tid >> 9, sl2 = tid & 511;   // x-staging split over 1024 thr
  const bh8* wp = (const bh8*)wsw;

#define WF(g,kt) wp[((size_t)((lsel*32 + (g)*8 + u)*8 + (kt))*64) + lane]
#define PW(kt)   (*(const bh8*)&WPOOL[((w*5 + (kt))*64 + lane)*8])

  for (int idx = tid; idx < 2048; idx += 1024){
    H0hi[1][idx] = 0; H0lo[1][idx] = 0;   // h0(-1)
    H1hi[0][idx] = 0; H1lo[0][idx] = 0;   // h1(-1)
  }
  float bz[4];
  #pragma unroll
  for (int g = 0; g < 4; g++)
    bz[g] = wsbias[lsel*512 + (g*8 + u)*16 + col];
  float cst[4] = {0,0,0,0};

  // ---- weight residency setup (once) ----
  bh8 wr0[7], wr1[7];
  #pragma unroll
  for (int kt = 0; kt < 7; kt++){
    wr0[kt] = WF(0, kt);
    wr1[kt] = WF(1, kt);
  }
  #pragma unroll
  for (int p = 0; p < 5; p++){
    bh8 v = WF(2, p);
    *(bh8*)&WPOOL[((w*5 + p)*64 + lane)*8] = v;   // wave-local pool slot
  }

  // stage x(0) into XA[0] (each thread moves 8B)
  {
    float2 v = *(const float2*)(xfrag + ((size_t)bt*2 + pl2)*2048 + (size_t)sl2*4);
    *(float2*)((pl2 ? XAlo[0] : XAhi[0]) + sl2*4) = v;
  }
  __syncthreads();

  for (int i = 0; i <= S_; i++){
    const int cb = i & 1, pb = cb ^ 1;
    // prefetch x(i+1) (latency hidden under the MFMA phase)
    int tp = (i+1 < S_) ? i+1 : S_-1;
    float2 pf = *(const float2*)(xfrag + (((size_t)tp*64 + bt)*2 + pl2)*2048 + (size_t)sl2*4);

    const bool act = t1 ? (i >= 1) : (i < S_);
    if (act){
      fx4 acc[4];
      #pragma unroll
      for (int g = 0; g < 4; g++)
        acc[g] = (fx4){bz[g], bz[g], bz[g], bz[g]};
      bh8 ah, al;
#define AFRAG(kt) { \
      const short* ph_; const short* pl_; \
      if (!t1){ ph_ = ((kt) < 4) ? &XAhi[cb][(kt)*512 + lane*8] : &H0hi[pb][((kt)-4)*512 + lane*8]; \
                pl_ = ((kt) < 4) ? &XAlo[cb][(kt)*512 + lane*8] : &H0lo[pb][((kt)-4)*512 + lane*8]; } \
      else    { ph_ = ((kt) < 4) ? &H0hi[pb][(kt)*512 + lane*8] : &H1hi[pb][((kt)-4)*512 + lane*8]; \
                pl_ = ((kt) < 4) ? &H0lo[pb][(kt)*512 + lane*8] : &H1lo[pb][((kt)-4)*512 + lane*8]; } \
      ah = *(const bh8*)ph_; al = *(const bh8*)pl_; }
#define MM(g, W) \
      acc[g] = __builtin_amdgcn_mfma_f32_16x16x32_bf16(ah, (W), acc[g], 0, 0, 0); \
      acc[g] = __builtin_amdgcn_mfma_f32_16x16x32_bf16(al, (W), acc[g], 0, 0, 0);

      // streamed weights, issued in staged groups to bound register liveness
      bh8 s30 = WF(3,0), s31 = WF(3,1), s32 = WF(3,2), s33 = WF(3,3);
      __builtin_amdgcn_s_setprio(1);
      AFRAG(0); MM(0, wr0[0]); MM(1, wr1[0]); MM(2, PW(0)); MM(3, s30);
      AFRAG(1); MM(0, wr0[1]); MM(1, wr1[1]); MM(2, PW(1)); MM(3, s31);
      bh8 s34 = WF(3,4), s35 = WF(3,5), s25 = WF(2,5);
      AFRAG(2); MM(0, wr0[2]); MM(1, wr1[2]); MM(2, PW(2)); MM(3, s32);
      AFRAG(3); MM(0, wr0[3]); MM(1, wr1[3]); MM(2, PW(3)); MM(3, s33);
      bh8 s26 = WF(2,6), s36 = WF(3,6);
      AFRAG(4); MM(0, wr0[4]); MM(1, wr1[4]); MM(2, PW(4)); MM(3, s34);
      bh8 s27 = WF(2,7), s37 = WF(3,7), s07 = WF(0,7), s17 = WF(1,7);
      AFRAG(5); MM(0, wr0[5]); MM(1, wr1[5]); MM(2, s25); MM(3, s35);
      AFRAG(6); MM(0, wr0[6]); MM(1, wr1[6]); MM(2, s26); MM(3, s36);
      AFRAG(7); MM(0, s07);    MM(1, s17);    MM(2, s27); MM(3, s37);
      __builtin_amdgcn_s_setprio(0);

      float (*XH)[132] = t1 ? XH1f : XH0f;
      #pragma unroll
      for (int r = 0; r < 4; r++){
        float cc = sigm(acc[1][r])*cst[r] + sigm(acc[0][r])*tanh_(acc[2][r]);
        cst[r] = cc;
        XH[quad*4 + r][u*16 + col] = sigm(acc[3][r])*tanh_(cc);
      }
      // wave-local convert: wave u transposes its own 16 cols into half of
      // A-frag slice kt4 = u>>1 (half = u&1). Lanes 0-31 write the hi plane,
      // lanes 32-63 the lo plane. Same-wave LDS dep -> lgkmcnt-ordered.
      {
        const int mm = lane & 15, qq = (lane >> 4) & 1, phase = lane >> 5;
        bh8 hv, lv;
        frag_convert_row(&XH[mm][u*16 + qq*8], hv, lv);
        const int off = (u >> 1)*512 + ((2*(u & 1) + qq)*16 + mm)*8;
        short* dsth = t1 ? &H1hi[cb][off] : &H0hi[cb][off];
        short* dstl = t1 ? &H1lo[cb][off] : &H0lo[cb][off];
        short* dst  = phase ? dstl : dsth;
        bh8   val   = phase ? lv : hv;
        *(bh8*)dst = val;
      }
    }
    // park x(i+1) into the other parity buffer (disjoint from this iter's reads)
    *(float2*)((pl2 ? XAlo[pb] : XAhi[pb]) + sl2*4) = pf;
    __syncthreads();   // publish H0[cb], H1[cb], XA[pb] for iter i+1
  }
  // XH1f holds h1(t=49) (written by team1 at iter 50, barrier'd). Fused head1.
  {
    const int mm2 = tid >> 6;          // 16 rows
    const int cc2 = tid & 63;          // 64 cols
    float s = b1[cc2];
    #pragma unroll 8
    for (int k = 0; k < 128; k++) s += XH1f[mm2][k]*W1[cc2*128 + k];
    s = fmaxf(s, 0.f);
    hidden_bf[(size_t)(bt*16 + mm2)*64 + cc2] = (short)f2bf(s);
  }
#undef WF
#undef PW
#undef AFRAG
#undef MM
}

// ---------------------------------------------------------------------------
// logits = hidden @ W2^T + b2. Block = (chunk of 32 n-tiles) x (one m-tile);
// results re-staged through LDS so global stores are 512B-contiguous rows.
// XCD-aware bijective swizzle: each XCD works chunk-contiguously so its W2
// working set (~1.6MB) stays resident in its own 4MB L2 (T1).
__global__ __launch_bounds__(256) void head2(
    const short* __restrict__ hid, const short* __restrict__ w2,
    const float* __restrict__ b2, float* __restrict__ out){
  __shared__ __align__(16) float HS[4][16][132];
  const int tid = threadIdx.x;
  const int w = tid >> 6, lane = tid & 63;
  const int col = lane & 15, quad = lane >> 4;
  const int bsw = blockIdx.x;                    // 12544 = 8 * 1568
  const int wg  = (bsw & 7)*1568 + (bsw >> 3);   // bijective XCD swizzle
  const int mt = wg & 63;
  const int chunk = wg >> 6;                     // 196 chunks
  const bh8* hp = (const bh8*)hid;
  bh8 a0 = hp[(size_t)(mt*16 + col)*8 + quad];
  bh8 a1 = hp[(size_t)(mt*16 + col)*8 + 4 + quad];
  const bh8* wpt = (const bh8*)w2;
  #pragma unroll
  for (int i = 0; i < 8; i++){
    int nt = chunk*32 + w*8 + i;
    if (nt < 6251){
      int n = nt*16 + col;
      bh8 b0v = wpt[(size_t)n*8 + quad];
      bh8 b1v = wpt[(size_t)n*8 + 4 + quad];
      fx4 a = {0.f,0.f,0.f,0.f};
      a = __builtin_amdgcn_mfma_f32_16x16x32_bf16(a0, b0v, a, 0, 0, 0);
      a = __builtin_amdgcn_mfma_f32_16x16x32_bf16(a1, b1v, a, 0, 0, 0);
      float bias = (n < NOUT) ? b2[n] : 0.f;
      #pragma unroll
      for (int r = 0; r < 4; r++) HS[w][quad*4 + r][i*16 + col] = a[r] + bias;
    }
  }
  __syncthreads();
  const long rowbase = (long)mt*16;
  const int n0 = chunk*512 + w*128;
  #pragma unroll
  for (int p = 0; p < 8; p++){
    int row = p*2 + (lane >> 5);
    int c4 = (lane & 31)*4;
    int gc = n0 + c4;
    float4 v = *(const float4*)&HS[w][row][c4];
    if (gc + 3 < NOUT){
      *(float4*)&out[(rowbase + row)*NOUT + gc] = v;
    } else {
      float vv[4] = {v.x, v.y, v.z, v.w};
      #pragma unroll
      for (int k2 = 0; k2 < 4; k2++)
        if (gc + k2 < NOUT) out[(rowbase + row)*NOUT + gc + k2] = vv[k2];
    }
  }
}

// ---------------------------------------------------------------------------
extern "C" void kernel_launch(void* const* d_in, const int* in_sizes, int n_in,
                              void* d_out, int out_size, void* d_ws, size_t ws_size,
                              hipStream_t stream){
  const int*   prod = (const int*)  d_in[0];
  const int*   cat  = (const int*)  d_in[1];
  const float* age  = (const float*)d_in[2];
  const float* ts   = (const float*)d_in[3];
  const float* gen  = (const float*)d_in[4];
  const float* embp = (const float*)d_in[5];
  const float* embc = (const float*)d_in[6];
  const float* Wts  = (const float*)d_in[7];
  const float* bts  = (const float*)d_in[8];
  const float* Wuf  = (const float*)d_in[9];
  const float* bufv = (const float*)d_in[10];
  const float* Wih0 = (const float*)d_in[11];
  const float* Whh0 = (const float*)d_in[12];
  const float* bih0 = (const float*)d_in[13];
  const float* bhh0 = (const float*)d_in[14];
  const float* Wih1 = (const float*)d_in[15];
  const float* Whh1 = (const float*)d_in[16];
  const float* bih1 = (const float*)d_in[17];
  const float* bhh1 = (const float*)d_in[18];
  const float* W1   = (const float*)d_in[19];
  const float* b1   = (const float*)d_in[20];
  const float* W2   = (const float*)d_in[21];
  const float* b2   = (const float*)d_in[22];
  float* out = (float*)d_out;

  char* ws = (char*)d_ws;
  short* ws_x    = (short*)(ws);               // xfrag: 26,214,400 B
  short* ws_w    = (short*)(ws + 26214400);    // lstm W frags: 524,288 B
  float* ws_bias = (float*)(ws + 26738688);    // [2][512] f32: 4,096 B
  short* ws_hid  = (short*)(ws + 26742784);    // hidden bf16 [1024][64]: 131,072 B
  short* ws_w2   = (short*)(ws + 26873856);    // W2 bf16 [100016][64]: 12,802,048 B

  prep_lstm_w<<<128, 256, 0, stream>>>(Wih0, Whh0, bih0, bhh0,
                                       Wih1, Whh1, bih1, bhh1, ws_w, ws_bias);
  prep_w2<<<25004, 256, 0, stream>>>(W2, ws_w2);
  features<<<3200, 256, 0, stream>>>(prod, cat, age, ts, gen, embp, embc,
                                     Wts, bts, Wuf, bufv, ws_x);
  lstm_kernel<<<64, 1024, 0, stream>>>(ws_x, ws_w, ws_bias, W1, b1, ws_hid);
  head2<<<196*64, 256, 0, stream>>>(ws_hid, ws_w2, b2, out);
}

// Round 4
// 1019.185 us; speedup vs baseline: 1.0194x; 1.0194x over previous
//
#include <hip/hip_runtime.h>

#define B_    1024
#define S_    50
#define L_    20
#define NOUT  100001

typedef __attribute__((ext_vector_type(8))) short bh8;   // 8 bf16 (4 VGPRs)
typedef __attribute__((ext_vector_type(4))) float fx4;   // MFMA C/D

__device__ __forceinline__ unsigned short f2bf(float x){
  unsigned u = __float_as_uint(x);
  unsigned r = (u + 0x7FFFu + ((u >> 16) & 1u)) >> 16;   // RNE
  return (unsigned short)r;
}
__device__ __forceinline__ float bf2f(unsigned short h){
  return __uint_as_float(((unsigned)h) << 16);
}
__device__ __forceinline__ float sigm(float x){
  return __builtin_amdgcn_rcpf(1.f + __expf(-x));
}
__device__ __forceinline__ float tanh_(float x){
  return 1.f - 2.f*__builtin_amdgcn_rcpf(__expf(2.f*x) + 1.f);
}

// split x into bf16 hi + bf16 lo (hi+lo == x to ~2^-17 rel)
__device__ __forceinline__ void frag_convert_row(const float* src, bh8& hv, bh8& lv){
  #pragma unroll
  for (int j = 0; j < 8; j++){
    float x = src[j];
    unsigned short hb = f2bf(x);
    hv[j] = (short)hb;
    lv[j] = (short)f2bf(x - bf2f(hb));
  }
}

// ---------------------------------------------------------------------------
// LSTM weight prep: single bf16 plane in per-lane B-fragment order.
// Layout: [layer(2)][nt(32)][kt(8)][lane(64)][8 bf16]
// B-frag (16x16x32): n = nt*16 + (lane&15), k = kt*32 + (lane>>4)*8 + j.
// K=256 = [x(128) | h(128)] -> W_ih cols then W_hh cols. bias = b_ih + b_hh.
__global__ __launch_bounds__(256) void prep_lstm_w(
    const float* __restrict__ Wih0, const float* __restrict__ Whh0,
    const float* __restrict__ bih0, const float* __restrict__ bhh0,
    const float* __restrict__ Wih1, const float* __restrict__ Whh1,
    const float* __restrict__ bih1, const float* __restrict__ bhh1,
    short* __restrict__ wsw, float* __restrict__ wsbias){
  int tid = blockIdx.x*256 + threadIdx.x;       // 32768 total
  if (tid < 1024){
    int l = tid >> 9, n = tid & 511;
    wsbias[l*512 + n] = l ? (bih1[n] + bhh1[n]) : (bih0[n] + bhh0[n]);
  }
  if (tid >= 32768) return;
  int lane = tid & 63;
  int kt   = (tid >> 6) & 7;
  int nt   = (tid >> 9) & 31;
  int l    = tid >> 14;
  const float* Wih = l ? Wih1 : Wih0;
  const float* Whh = l ? Whh1 : Whh0;
  int n = nt*16 + (lane & 15);
  int kbase = kt*32 + (lane >> 4)*8;
  size_t base = ((((size_t)l*32 + nt)*8 + kt)*64 + lane)*8;
  for (int j = 0; j < 8; j++){
    int k = kbase + j;
    float w = (k < 128) ? Wih[n*128 + k] : Whh[n*128 + (k - 128)];
    wsw[base + j] = (short)f2bf(w);
  }
}

// W2 -> bf16, padded to 100016 rows (zeros).
__global__ __launch_bounds__(256) void prep_w2(const float* __restrict__ W2,
                                               short* __restrict__ out){
  long i = (long)blockIdx.x*256 + threadIdx.x;  // 100016*64 = 6,401,024
  if (i >= 100016L*64) return;
  long row = i >> 6;
  float v = (row < NOUT) ? W2[i] : 0.f;
  out[i] = (short)f2bf(v);
}

// ---------------------------------------------------------------------------
// Features -> x in A-fragment order, bf16 hi/lo planes.
// xfrag layout: [s(50)][bt(64)][plane(2)][kt(4)][lane(64)][8 bf16]
// Block = (bt, s): 16 batch rows x 128 features.
__global__ __launch_bounds__(256) void features(
    const int* __restrict__ pidx, const int* __restrict__ cidx,
    const float* __restrict__ age, const float* __restrict__ ts,
    const float* __restrict__ gender,
    const float* __restrict__ embp, const float* __restrict__ embc,
    const float* __restrict__ Wts, const float* __restrict__ bts,
    const float* __restrict__ Wuf, const float* __restrict__ bufv,
    short* __restrict__ xfrag){
  const int bx = blockIdx.x;
  const int bt = bx & 63, s = bx >> 6;
  const int b0 = bt*16;
  const int tid = threadIdx.x;
  __shared__ int pi[320], ci[320];
  __shared__ __align__(16) float XF[16][132];
  for (int i = tid; i < 640; i += 256){
    if (i < 320){
      int row = i/20, l = i - row*20;
      pi[i] = pidx[((size_t)(b0+row)*S_ + s)*L_ + l];
    } else {
      int j = i - 320;
      int row = j/20, l = j - row*20;
      ci[j] = cidx[((size_t)(b0+row)*S_ + s)*L_ + l];
    }
  }
  __syncthreads();
  const int m = tid >> 4, fg = tid & 15;
  float a[8];
  if (fg < 8){
    int f0 = fg*8;
    float4 s0 = {0,0,0,0}, s1 = {0,0,0,0};
    for (int l = 0; l < L_; l++){
      const float4* p = (const float4*)(embp + (size_t)pi[m*20+l]*64 + f0);
      float4 u = p[0], v = p[1];
      s0.x += u.x; s0.y += u.y; s0.z += u.z; s0.w += u.w;
      s1.x += v.x; s1.y += v.y; s1.z += v.z; s1.w += v.w;
    }
    a[0]=s0.x*0.05f; a[1]=s0.y*0.05f; a[2]=s0.z*0.05f; a[3]=s0.w*0.05f;
    a[4]=s1.x*0.05f; a[5]=s1.y*0.05f; a[6]=s1.z*0.05f; a[7]=s1.w*0.05f;
  } else if (fg < 12){
    int f0 = (fg-8)*8;
    float4 s0 = {0,0,0,0}, s1 = {0,0,0,0};
    for (int l = 0; l < L_; l++){
      const float4* p = (const float4*)(embc + (size_t)ci[m*20+l]*32 + f0);
      float4 u = p[0], v = p[1];
      s0.x += u.x; s0.y += u.y; s0.z += u.z; s0.w += u.w;
      s1.x += v.x; s1.y += v.y; s1.z += v.z; s1.w += v.w;
    }
    a[0]=s0.x*0.05f; a[1]=s0.y*0.05f; a[2]=s0.z*0.05f; a[3]=s0.w*0.05f;
    a[4]=s1.x*0.05f; a[5]=s1.y*0.05f; a[6]=s1.z*0.05f; a[7]=s1.w*0.05f;
  } else if (fg < 14){
    int j0 = (fg-12)*8;
    float tv = ts[(size_t)(b0+m)*S_ + s];
    #pragma unroll
    for (int e = 0; e < 8; e++) a[e] = tv*Wts[j0+e] + bts[j0+e];
  } else {
    int j0 = (fg-14)*8;
    float av = age[b0+m], gv = gender[b0+m];
    #pragma unroll
    for (int e = 0; e < 8; e++){
      int j = j0+e;
      a[e] = av*Wuf[2*j] + gv*Wuf[2*j+1] + bufv[j];
    }
  }
  {
    int f0 = fg*8;
    *(float4*)&XF[m][f0]   = (float4){a[0],a[1],a[2],a[3]};
    *(float4*)&XF[m][f0+4] = (float4){a[4],a[5],a[6],a[7]};
  }
  __syncthreads();
  // phase 2: emit fragment-order hi/lo planes
  const int kt = tid >> 6, ls = tid & 63;
  const int mm = ls & 15, a2 = ls >> 4;
  bh8 hv, lv;
  frag_convert_row(&XF[mm][kt*32 + a2*8], hv, lv);
  size_t ob = ((((size_t)s*64 + bt)*2 + 0)*4 + kt)*512 + (size_t)ls*8;
  *(bh8*)(xfrag + ob)        = hv;   // plane 0 (hi)
  *(bh8*)(xfrag + ob + 2048) = lv;   // plane 1 (lo)
}

// ---------------------------------------------------------------------------
// pregate0: hoist the NON-RECURRENT layer-0 x-GEMM out of the recurrence.
// pg[t][bt][u(8)][g(4)][lane(64)] = float4 (C-frag rows r0..3) =
//   bias0 + x(t) @ W_ih0^T, computed with the EXACT kt0..3 hi/lo MM order
//   the recurrent kernel used -> lstm resumes the same chain at kt4..7,
//   bitwise-identical accumulation. 3200 blocks -> all 256 CUs (the lstm
//   kernel can only use 64).
__global__ __launch_bounds__(256) void pregate0(
    const short* __restrict__ xfrag, const short* __restrict__ wsw,
    const float* __restrict__ wsbias, float* __restrict__ pg){
  const int bx = blockIdx.x;
  const int bt = bx & 63, s = bx >> 6;
  const int tid = threadIdx.x;
  const int wv = tid >> 6, lane = tid & 63;
  const int col = lane & 15;
  const bh8* wp = (const bh8*)wsw;
  // A-frags kt0..3, hi/lo planes (same values for all 4 waves)
  bh8 ah[4], al[4];
  #pragma unroll
  for (int kt = 0; kt < 4; kt++){
    size_t ob = ((((size_t)s*64 + bt)*2 + 0)*4 + kt)*512 + (size_t)lane*8;
    ah[kt] = *(const bh8*)(xfrag + ob);
    al[kt] = *(const bh8*)(xfrag + ob + 2048);
  }
  fx4* pgout = (fx4*)pg;
  #pragma unroll
  for (int e = 0; e < 2; e++){
    const int uu = wv*2 + e;
    #pragma unroll
    for (int g = 0; g < 4; g++){
      float bzv = wsbias[(g*8 + uu)*16 + col];
      fx4 acc = (fx4){bzv, bzv, bzv, bzv};
      #pragma unroll
      for (int kt = 0; kt < 4; kt++){
        bh8 bb = wp[(size_t)((g*8 + uu)*8 + kt)*64 + lane];
        acc = __builtin_amdgcn_mfma_f32_16x16x32_bf16(ah[kt], bb, acc, 0, 0, 0);
        acc = __builtin_amdgcn_mfma_f32_16x16x32_bf16(al[kt], bb, acc, 0, 0, 0);
      }
      pgout[((((size_t)s*64 + bt)*8 + uu)*4 + g)*64 + lane] = acc;
    }
  }
}

// ---------------------------------------------------------------------------
// 2-layer LSTM recurrence, WEIGHT-STATIONARY with asm-pinned registers.
// 64 blocks x 1024 thr (16 waves, 4/SIMD). Waves 0-7 (team0): layer0 step i,
// starting from precomputed pregate (kt0..3 done) -> only W_hh0 (kt4..7),
// 16 frags, ALL pinned in registers: team0 streams ZERO weight bytes.
// Waves 8-15 (team1): layer1 step i-1, 32 frags: gates 0,1 pinned in
// registers (16 frags), gate 2 in a wave-local LDS pool (64KB), gate 3
// streamed from L2 (8KB/wave/step). Per-CU weight stream: 512KB -> 64KB/step.
// asm volatile("" : "+v"(w)) after load makes rematerialization illegal ->
// the round-3 failure (compiler sinking the loads back into the loop,
// VGPR_Count stuck at 64) cannot recur.
// Per-accumulator FP order identical to round 2 -> identical absmax.
__global__ __launch_bounds__(1024, 4) void lstm_pre(
    const float* __restrict__ pg0, const short* __restrict__ wsw,
    const float* __restrict__ wsbias,
    const float* __restrict__ W1, const float* __restrict__ b1,
    short* __restrict__ hidden_bf){
  __shared__ __align__(16) short H0hi[2][2048], H0lo[2][2048]; // h0(t) frags
  __shared__ __align__(16) short H1hi[2][2048], H1lo[2][2048]; // h1(t) frags
  __shared__ __align__(16) float XH0f[16][132], XH1f[16][132]; // f32 C-tiles
  __shared__ __align__(16) short WPOOL[32768];                 // 64KB: team1 gate2
  const int tid  = threadIdx.x;
  const int w    = tid >> 6, lane = tid & 63;
  const int col  = lane & 15, quad = lane >> 4;
  const int bt   = blockIdx.x;
  const int u    = w & 7;                 // team-wave index (0..7)
  const bool t1  = (w >= 8);              // team1 = layer 1
  const bh8* wp = (const bh8*)wsw;
  const fx4* pgp = (const fx4*)pg0;

#define WFL(l,g,kt) wp[((size_t)(((l)*32 + (g)*8 + u)*8 + (kt))*64) + lane]
#define PWP(kt)     (*(const bh8*)&WPOOL[((u*8 + (kt))*64 + lane)*8])

  for (int idx = tid; idx < 2048; idx += 1024){
    H0hi[1][idx] = 0; H0lo[1][idx] = 0;   // h0(-1)
    H1hi[0][idx] = 0; H1lo[0][idx] = 0;   // h1(-1)
  }
  float bz[4] = {0,0,0,0};
  if (t1){
    #pragma unroll
    for (int g = 0; g < 4; g++)
      bz[g] = wsbias[512 + (g*8 + u)*16 + col];
  }
  float cst[4] = {0,0,0,0};

  // ---- pinned weight residency (once) ----
  bh8 wpin[16];
  if (!t1){
    // team0: W_hh0 = gates 0..3, kt 4..7 -> wpin[g*4 + (kt-4)]
    #pragma unroll
    for (int g = 0; g < 4; g++)
      #pragma unroll
      for (int k4 = 0; k4 < 4; k4++)
        wpin[g*4 + k4] = WFL(0, g, 4 + k4);
  } else {
    // team1: gates 0,1 all kt -> wpin[g*8+kt]; gate 2 -> LDS pool
    #pragma unroll
    for (int g = 0; g < 2; g++)
      #pragma unroll
      for (int kt = 0; kt < 8; kt++)
        wpin[g*8 + kt] = WFL(1, g, kt);
    #pragma unroll
    for (int kt = 0; kt < 8; kt++){
      bh8 v = WFL(1, 2, kt);
      *(bh8*)&WPOOL[((u*8 + kt)*64 + lane)*8] = v;
    }
  }
  #pragma unroll
  for (int q = 0; q < 16; q++) asm volatile("" : "+v"(wpin[q]));

  // team0: prefetch pregate(0)
  fx4 pgv[4];
  if (!t1){
    #pragma unroll
    for (int g = 0; g < 4; g++)
      pgv[g] = pgp[((((size_t)0*64 + bt)*8 + u)*4 + g)*64 + lane];
  }
  __syncthreads();

#define MM2(g, W) \
      acc[g] = __builtin_amdgcn_mfma_f32_16x16x32_bf16(ah, (W), acc[g], 0, 0, 0); \
      acc[g] = __builtin_amdgcn_mfma_f32_16x16x32_bf16(al, (W), acc[g], 0, 0, 0);

  for (int i = 0; i <= S_; i++){
    const int cb = i & 1, pb = cb ^ 1;
    if (!t1){
      if (i < S_){
        fx4 acc[4];
        #pragma unroll
        for (int g = 0; g < 4; g++) acc[g] = pgv[g];
        // prefetch pregate(i+1) — latency hidden under this step's MFMAs
        if (i + 1 < S_){
          #pragma unroll
          for (int g = 0; g < 4; g++)
            pgv[g] = pgp[((((size_t)(i+1)*64 + bt)*8 + u)*4 + g)*64 + lane];
        }
        bh8 ah, al;
        __builtin_amdgcn_s_setprio(1);
        #pragma unroll
        for (int k4 = 0; k4 < 4; k4++){
          ah = *(const bh8*)&H0hi[pb][k4*512 + lane*8];
          al = *(const bh8*)&H0lo[pb][k4*512 + lane*8];
          MM2(0, wpin[0*4 + k4]); MM2(1, wpin[1*4 + k4]);
          MM2(2, wpin[2*4 + k4]); MM2(3, wpin[3*4 + k4]);
        }
        __builtin_amdgcn_s_setprio(0);
        #pragma unroll
        for (int r = 0; r < 4; r++){
          float cc = sigm(acc[1][r])*cst[r] + sigm(acc[0][r])*tanh_(acc[2][r]);
          cst[r] = cc;
          XH0f[quad*4 + r][u*16 + col] = sigm(acc[3][r])*tanh_(cc);
        }
        // wave-local convert into half of A-frag slice kt4 = u>>1
        {
          const int mm = lane & 15, qq = (lane >> 4) & 1, phase = lane >> 5;
          bh8 hv, lv;
          frag_convert_row(&XH0f[mm][u*16 + qq*8], hv, lv);
          const int off = (u >> 1)*512 + ((2*(u & 1) + qq)*16 + mm)*8;
          short* dst = phase ? &H0lo[cb][off] : &H0hi[cb][off];
          bh8 val = phase ? lv : hv;
          *(bh8*)dst = val;
        }
      }
    } else {
      if (i >= 1){
        fx4 acc[4];
        #pragma unroll
        for (int g = 0; g < 4; g++)
          acc[g] = (fx4){bz[g], bz[g], bz[g], bz[g]};
        bh8 ah, al;
        // streamed gate-3 weights, staged 4+4 to bound liveness
        bh8 s30 = WFL(1,3,0), s31 = WFL(1,3,1), s32 = WFL(1,3,2), s33 = WFL(1,3,3);
        __builtin_amdgcn_s_setprio(1);
        #pragma unroll
        for (int kt = 0; kt < 4; kt++){
          ah = *(const bh8*)&H0hi[pb][kt*512 + lane*8];
          al = *(const bh8*)&H0lo[pb][kt*512 + lane*8];
          bh8 s3 = (kt==0)?s30:(kt==1)?s31:(kt==2)?s32:s33;
          MM2(0, wpin[kt]); MM2(1, wpin[8 + kt]); MM2(2, PWP(kt)); MM2(3, s3);
        }
        bh8 s34 = WFL(1,3,4), s35 = WFL(1,3,5), s36 = WFL(1,3,6), s37 = WFL(1,3,7);
        #pragma unroll
        for (int k4 = 0; k4 < 4; k4++){
          ah = *(const bh8*)&H1hi[pb][k4*512 + lane*8];
          al = *(const bh8*)&H1lo[pb][k4*512 + lane*8];
          bh8 s3 = (k4==0)?s34:(k4==1)?s35:(k4==2)?s36:s37;
          MM2(0, wpin[4 + k4]); MM2(1, wpin[12 + k4]); MM2(2, PWP(4 + k4)); MM2(3, s3);
        }
        __builtin_amdgcn_s_setprio(0);
        #pragma unroll
        for (int r = 0; r < 4; r++){
          float cc = sigm(acc[1][r])*cst[r] + sigm(acc[0][r])*tanh_(acc[2][r]);
          cst[r] = cc;
          XH1f[quad*4 + r][u*16 + col] = sigm(acc[3][r])*tanh_(cc);
        }
        {
          const int mm = lane & 15, qq = (lane >> 4) & 1, phase = lane >> 5;
          bh8 hv, lv;
          frag_convert_row(&XH1f[mm][u*16 + qq*8], hv, lv);
          const int off = (u >> 1)*512 + ((2*(u & 1) + qq)*16 + mm)*8;
          short* dst = phase ? &H1lo[cb][off] : &H1hi[cb][off];
          bh8 val = phase ? lv : hv;
          *(bh8*)dst = val;
        }
      }
    }
    __syncthreads();   // publish H0[cb], H1[cb] for iter i+1
  }
  // XH1f holds h1(t=49). Fused head1.
  {
    const int mm2 = tid >> 6;          // 16 rows
    const int cc2 = tid & 63;          // 64 cols
    float s = b1[cc2];
    #pragma unroll 8
    for (int k = 0; k < 128; k++) s += XH1f[mm2][k]*W1[cc2*128 + k];
    s = fmaxf(s, 0.f);
    hidden_bf[(size_t)(bt*16 + mm2)*64 + cc2] = (short)f2bf(s);
  }
#undef WFL
#undef PWP
#undef MM2
}

// ---------------------------------------------------------------------------
// Legacy (round-2) recurrence: used only if the workspace is too small for
// the pregate buffer. Known-good at 343 us.
__global__ __launch_bounds__(1024, 4) void lstm_legacy(
    const short* __restrict__ xfrag, const short* __restrict__ wsw,
    const float* __restrict__ wsbias,
    const float* __restrict__ W1, const float* __restrict__ b1,
    short* __restrict__ hidden_bf){
  __shared__ __align__(16) short XAhi[2][2048], XAlo[2][2048];
  __shared__ __align__(16) short H0hi[2][2048], H0lo[2][2048];
  __shared__ __align__(16) short H1hi[2][2048], H1lo[2][2048];
  __shared__ __align__(16) float XH0f[16][132], XH1f[16][132];
  const int tid  = threadIdx.x;
  const int w    = tid >> 6, lane = tid & 63;
  const int col  = lane & 15, quad = lane >> 4;
  const int bt   = blockIdx.x;
  const int u    = w & 7;
  const bool t1  = (w >= 8);
  const int lsel = t1 ? 1 : 0;
  const int pl2  = tid >> 9, sl2 = tid & 511;
  const bh8* wp = (const bh8*)wsw;

  for (int idx = tid; idx < 2048; idx += 1024){
    H0hi[1][idx] = 0; H0lo[1][idx] = 0;
    H1hi[0][idx] = 0; H1lo[0][idx] = 0;
  }
  float bz[4];
  #pragma unroll
  for (int g = 0; g < 4; g++)
    bz[g] = wsbias[lsel*512 + (g*8 + u)*16 + col];
  float cst[4] = {0,0,0,0};
  {
    float2 v = *(const float2*)(xfrag + ((size_t)bt*2 + pl2)*2048 + (size_t)sl2*4);
    *(float2*)((pl2 ? XAlo[0] : XAhi[0]) + sl2*4) = v;
  }
  __syncthreads();

  for (int i = 0; i <= S_; i++){
    const int cb = i & 1, pb = cb ^ 1;
    int tp = (i+1 < S_) ? i+1 : S_-1;
    float2 pf = *(const float2*)(xfrag + (((size_t)tp*64 + bt)*2 + pl2)*2048 + (size_t)sl2*4);

    const bool act = t1 ? (i >= 1) : (i < S_);
    if (act){
      fx4 acc[4];
      #pragma unroll
      for (int g = 0; g < 4; g++)
        acc[g] = (fx4){bz[g], bz[g], bz[g], bz[g]};
      __builtin_amdgcn_s_setprio(1);
      #pragma unroll
      for (int kt = 0; kt < 8; kt++){
        const short* ph;
        const short* pl;
        if (!t1){
          ph = (kt < 4) ? &XAhi[cb][kt*512 + lane*8] : &H0hi[pb][(kt-4)*512 + lane*8];
          pl = (kt < 4) ? &XAlo[cb][kt*512 + lane*8] : &H0lo[pb][(kt-4)*512 + lane*8];
        } else {
          ph = (kt < 4) ? &H0hi[pb][kt*512 + lane*8] : &H1hi[pb][(kt-4)*512 + lane*8];
          pl = (kt < 4) ? &H0lo[pb][kt*512 + lane*8] : &H1lo[pb][(kt-4)*512 + lane*8];
        }
        bh8 ah = *(const bh8*)ph;
        bh8 al = *(const bh8*)pl;
        #pragma unroll
        for (int g = 0; g < 4; g++){
          bh8 bb = wp[(size_t)((lsel*32 + g*8 + u)*8 + kt)*64 + lane];
          acc[g] = __builtin_amdgcn_mfma_f32_16x16x32_bf16(ah, bb, acc[g], 0, 0, 0);
          acc[g] = __builtin_amdgcn_mfma_f32_16x16x32_bf16(al, bb, acc[g], 0, 0, 0);
        }
      }
      __builtin_amdgcn_s_setprio(0);
      float (*XH)[132] = t1 ? XH1f : XH0f;
      #pragma unroll
      for (int r = 0; r < 4; r++){
        float cc = sigm(acc[1][r])*cst[r] + sigm(acc[0][r])*tanh_(acc[2][r]);
        cst[r] = cc;
        XH[quad*4 + r][u*16 + col] = sigm(acc[3][r])*tanh_(cc);
      }
      {
        const int mm = lane & 15, qq = (lane >> 4) & 1, phase = lane >> 5;
        bh8 hv, lv;
        frag_convert_row(&XH[mm][u*16 + qq*8], hv, lv);
        const int off = (u >> 1)*512 + ((2*(u & 1) + qq)*16 + mm)*8;
        short* dsth = t1 ? &H1hi[cb][off] : &H0hi[cb][off];
        short* dstl = t1 ? &H1lo[cb][off] : &H0lo[cb][off];
        short* dst  = phase ? dstl : dsth;
        bh8   val   = phase ? lv : hv;
        *(bh8*)dst = val;
      }
    }
    *(float2*)((pl2 ? XAlo[pb] : XAhi[pb]) + sl2*4) = pf;
    __syncthreads();
  }
  {
    const int mm2 = tid >> 6;
    const int cc2 = tid & 63;
    float s = b1[cc2];
    #pragma unroll 8
    for (int k = 0; k < 128; k++) s += XH1f[mm2][k]*W1[cc2*128 + k];
    s = fmaxf(s, 0.f);
    hidden_bf[(size_t)(bt*16 + mm2)*64 + cc2] = (short)f2bf(s);
  }
}

// ---------------------------------------------------------------------------
// logits = hidden @ W2^T + b2. Block = (chunk of 32 n-tiles) x (one m-tile);
// results re-staged through LDS so global stores are 512B-contiguous rows.
__global__ __launch_bounds__(256) void head2(
    const short* __restrict__ hid, const short* __restrict__ w2,
    const float* __restrict__ b2, float* __restrict__ out){
  __shared__ __align__(16) float HS[4][16][132];
  const int tid = threadIdx.x;
  const int w = tid >> 6, lane = tid & 63;
  const int col = lane & 15, quad = lane >> 4;
  const int mt = blockIdx.x & 63;
  const int chunk = blockIdx.x >> 6;       // 196 chunks
  const bh8* hp = (const bh8*)hid;
  bh8 a0 = hp[(size_t)(mt*16 + col)*8 + quad];
  bh8 a1 = hp[(size_t)(mt*16 + col)*8 + 4 + quad];
  const bh8* wpt = (const bh8*)w2;
  #pragma unroll
  for (int i = 0; i < 8; i++){
    int nt = chunk*32 + w*8 + i;
    if (nt < 6251){
      int n = nt*16 + col;
      bh8 b0v = wpt[(size_t)n*8 + quad];
      bh8 b1v = wpt[(size_t)n*8 + 4 + quad];
      fx4 a = {0.f,0.f,0.f,0.f};
      a = __builtin_amdgcn_mfma_f32_16x16x32_bf16(a0, b0v, a, 0, 0, 0);
      a = __builtin_amdgcn_mfma_f32_16x16x32_bf16(a1, b1v, a, 0, 0, 0);
      float bias = (n < NOUT) ? b2[n] : 0.f;
      #pragma unroll
      for (int r = 0; r < 4; r++) HS[w][quad*4 + r][i*16 + col] = a[r] + bias;
    }
  }
  __syncthreads();
  const long rowbase = (long)mt*16;
  const int n0 = chunk*512 + w*128;
  #pragma unroll
  for (int p = 0; p < 8; p++){
    int row = p*2 + (lane >> 5);
    int c4 = (lane & 31)*4;
    int gc = n0 + c4;
    float4 v = *(const float4*)&HS[w][row][c4];
    if (gc + 3 < NOUT){
      *(float4*)&out[(rowbase + row)*NOUT + gc] = v;
    } else {
      float vv[4] = {v.x, v.y, v.z, v.w};
      #pragma unroll
      for (int k2 = 0; k2 < 4; k2++)
        if (gc + k2 < NOUT) out[(rowbase + row)*NOUT + gc + k2] = vv[k2];
    }
  }
}

// ---------------------------------------------------------------------------
extern "C" void kernel_launch(void* const* d_in, const int* in_sizes, int n_in,
                              void* d_out, int out_size, void* d_ws, size_t ws_size,
                              hipStream_t stream){
  const int*   prod = (const int*)  d_in[0];
  const int*   cat  = (const int*)  d_in[1];
  const float* age  = (const float*)d_in[2];
  const float* ts   = (const float*)d_in[3];
  const float* gen  = (const float*)d_in[4];
  const float* embp = (const float*)d_in[5];
  const float* embc = (const float*)d_in[6];
  const float* Wts  = (const float*)d_in[7];
  const float* bts  = (const float*)d_in[8];
  const float* Wuf  = (const float*)d_in[9];
  const float* bufv = (const float*)d_in[10];
  const float* Wih0 = (const float*)d_in[11];
  const float* Whh0 = (const float*)d_in[12];
  const float* bih0 = (const float*)d_in[13];
  const float* bhh0 = (const float*)d_in[14];
  const float* Wih1 = (const float*)d_in[15];
  const float* Whh1 = (const float*)d_in[16];
  const float* bih1 = (const float*)d_in[17];
  const float* bhh1 = (const float*)d_in[18];
  const float* W1   = (const float*)d_in[19];
  const float* b1   = (const float*)d_in[20];
  const float* W2   = (const float*)d_in[21];
  const float* b2   = (const float*)d_in[22];
  float* out = (float*)d_out;

  char* ws = (char*)d_ws;
  short* ws_x    = (short*)(ws);               // xfrag: 26,214,400 B
  short* ws_w    = (short*)(ws + 26214400);    // lstm W frags: 524,288 B
  float* ws_bias = (float*)(ws + 26738688);    // [2][512] f32: 4,096 B
  short* ws_hid  = (short*)(ws + 26742784);    // hidden bf16 [1024][64]: 131,072 B
  short* ws_w2   = (short*)(ws + 26873856);    // W2 bf16 [100016][64]: 12,802,048 B
  float* ws_pg   = (float*)(ws + 39675904);    // pregate0 f32: 104,857,600 B
  const size_t PRE_NEED = 39675904ULL + 104857600ULL;   // 144,533,504 B
  const bool pre = (ws_size >= PRE_NEED);

  prep_lstm_w<<<128, 256, 0, stream>>>(Wih0, Whh0, bih0, bhh0,
                                       Wih1, Whh1, bih1, bhh1, ws_w, ws_bias);
  prep_w2<<<25004, 256, 0, stream>>>(W2, ws_w2);
  features<<<3200, 256, 0, stream>>>(prod, cat, age, ts, gen, embp, embc,
                                     Wts, bts, Wuf, bufv, ws_x);
  if (pre){
    pregate0<<<3200, 256, 0, stream>>>(ws_x, ws_w, ws_bias, ws_pg);
    lstm_pre<<<64, 1024, 0, stream>>>(ws_pg, ws_w, ws_bias, W1, b1, ws_hid);
  } else {
    lstm_legacy<<<64, 1024, 0, stream>>>(ws_x, ws_w, ws_bias, W1, b1, ws_hid);
  }
  head2<<<196*64, 256, 0, stream>>>(ws_hid, ws_w2, b2, out);
}